// Round 8
// baseline (241.643 us; speedup 1.0000x reference)
//
#include <hip/hip_runtime.h>

// SparseActivation: per row of D=2048 fp32, keep top K=204 by |x|, scale D/K.
//
// Round-7 failed correctness: counted vmcnt over a MIXED load+store stream is
// unsound — on CDNA, loads retire in order among loads, stores in order among
// stores, but loads/stores retire OUT OF ORDER w.r.t. each other (store-ack at
// L2 ~100cy beats HBM load ~900cy). A wait of vmcnt(24) counting {L1,L2,S0,L3}
// can pass with S0 retired and L1 still in flight -> garbage reads.
// SOUND RULE used here: vmcnt(N) guarantees load batch L retired iff
// N <= (# LOADS issued after L). Stores contribute ZERO budget; unknown
// compiler VMEM issued younger only strengthens the wait. Hence stores go back
// to compiler __builtin_nontemporal_store (validated rounds 1-6), loads stay
// inline-asm (rounds 3-4 proved C++ prefetch gets sunk; asm pins them).
//
// Pipeline (decoupling theory, round-6 post-mortem): 8 rows/wave, 3 register
// buffers, depth 3 -> each row's load has ~2 search-rounds (~3-4k cy) of
// cover; waves drift freely instead of phase-locked burst/silent cadence.
//   prologue L0 L1 L2
//   r0..r5: W(16)=two younger load batches; r6: W(8); r7: W(0)
//
// Search: exact K-th largest via bracket bisection on |x| (free |src| mod on
// v_cmp). Warm-start probes near the N(0,1) expected K-th value (~1.648);
// every bracket update is backed by an exact count -> exact for ANY finite
// input. Bracket closed to hi==lo+1 => lo is the exact K-th pattern; boundary
// ties resolved by lowest-global-index rank (matches lax.top_k stability).

constexpr int D_DIM = 2048;
constexpr int K_SEL = 204;     // int(2048 * 0.1)
constexpr int NT    = 256;     // 4 waves/block
constexpr int RPW   = 8;       // rows per wave

typedef float f32x4 __attribute__((ext_vector_type(4)));

// Pipeline-proof 16B load: allocation + order pinned at issue point.
__device__ __forceinline__ f32x4 gload16(const f32x4* p) {
    f32x4 r;
    asm volatile("global_load_dwordx4 %0, %1, off" : "=v"(r) : "v"(p) : "memory");
    return r;
}

// Counted wait + scheduler fence (rule #18).
#define VMWAIT(n)                                                  \
    do {                                                           \
        asm volatile("s_waitcnt vmcnt(" #n ")" ::: "memory");      \
        __builtin_amdgcn_sched_barrier(0);                         \
    } while (0)

// Full-wave64 integer sum via DPP; returns total (uniform, via readlane 63).
__device__ __forceinline__ int dpp_reduce_add(int x) {
    x += __builtin_amdgcn_update_dpp(0, x, 0x111, 0xF, 0xF, true);  // row_shr:1
    x += __builtin_amdgcn_update_dpp(0, x, 0x112, 0xF, 0xF, true);  // row_shr:2
    x += __builtin_amdgcn_update_dpp(0, x, 0x114, 0xF, 0xF, true);  // row_shr:4
    x += __builtin_amdgcn_update_dpp(0, x, 0x118, 0xF, 0xF, true);  // row_shr:8
    x += __builtin_amdgcn_update_dpp(0, x, 0x142, 0xA, 0xF, false); // row_bcast:15
    x += __builtin_amdgcn_update_dpp(0, x, 0x143, 0xC, 0xF, false); // row_bcast:31
    return __builtin_amdgcn_readlane(x, 63);
}

// Exact wave-wide count of elements with |value| >= t (t > 0, finite data).
__device__ __forceinline__ int wave_count_ge(const f32x4 (&f)[8], float t) {
    int c0 = 0, c1 = 0, c2 = 0, c3 = 0;
#pragma unroll
    for (int b = 0; b < 8; ++b) {
        c0 += (__builtin_fabsf(f[b].x) >= t) ? 1 : 0;
        c1 += (__builtin_fabsf(f[b].y) >= t) ? 1 : 0;
        c2 += (__builtin_fabsf(f[b].z) >= t) ? 1 : 0;
        c3 += (__builtin_fabsf(f[b].w) >= t) ? 1 : 0;
    }
    return dpp_reduce_add((c0 + c1) + (c2 + c3));
}

__device__ __forceinline__ void process_row(const f32x4 (&f)[8], f32x4* op,
                                            const int lane) {
    const float scale = 2048.0f / 204.0f;

    // Bracket invariant: count(>= lo) >= K > count(>= hi)  (on abs patterns).
    unsigned lo = 0u, hi = 0x80000000u;
    unsigned thr = 0u;
    bool done = false;

    // ---- Warm-start probe ladder (speed heuristic only; exact regardless) --
    {
        const int c = wave_count_ge(f, 1.6484375f);              // 0x3FD30000
        if (c == K_SEL) { thr = 0x3FD30000u; done = true; }
        else if (c > K_SEL) lo = 0x3FD30000u; else hi = 0x3FD30000u;
    }
    if (!done) {
        const unsigned p2 = (lo != 0u) ? 0x3FD60000u             // 1.671875
                                       : 0x3FD00000u;            // 1.625
        const int c = wave_count_ge(f, __uint_as_float(p2));
        if (c == K_SEL) { thr = p2; done = true; }
        else if (c > K_SEL) lo = p2; else hi = p2;
    }
    if (!done) {
        unsigned p3 = 0u;
        if (hi == 0x80000000u)      p3 = 0x3FE00000u;            // 1.75 (cap)
        else if (lo == 0u)          p3 = 0x3FC80000u;            // 1.5625 (floor)
        if (p3 != 0u) {
            const int c = wave_count_ge(f, __uint_as_float(p3));
            if (c == K_SEL) { thr = p3; done = true; }
            else if (c > K_SEL) lo = p3; else hi = p3;
        }
    }
    if (!done && lo == 0u) {   // very rare: K-th below 1.5625
        const int c = wave_count_ge(f, 1.0f);                    // 0x3F800000
        if (c == K_SEL) { thr = 0x3F800000u; done = true; }
        else if (c > K_SEL) lo = 0x3F800000u; else hi = 0x3F800000u;
    }

    // ---- Integer bisection of the bracket; early exit at exact count K. ----
#pragma unroll 1
    while (!done && (hi - lo) > 1u) {
        const unsigned mid = (lo + hi) >> 1;   // lo < mid < hi guaranteed
        const int c = wave_count_ge(f, __uint_as_float(mid));
        if (c == K_SEL) { thr = mid; done = true; }
        else if (c > K_SEL) lo = mid; else hi = mid;
    }

    if (done) {
        // Exact top-K set == {|x| >= thr}; no tie handling needed.
        const float tf = __uint_as_float(thr);
#pragma unroll
        for (int b = 0; b < 8; ++b) {
            f32x4 w;
            w.x = (__builtin_fabsf(f[b].x) >= tf) ? f[b].x * scale : 0.0f;
            w.y = (__builtin_fabsf(f[b].y) >= tf) ? f[b].y * scale : 0.0f;
            w.z = (__builtin_fabsf(f[b].z) >= tf) ? f[b].z * scale : 0.0f;
            w.w = (__builtin_fabsf(f[b].w) >= tf) ? f[b].w * scale : 0.0f;
            __builtin_nontemporal_store(w, op + b * 64 + lane);
        }
        return;
    }

    // Bracket closed: lo is the exact K-th largest pattern
    // (count(>=lo) > K since lo never hit count==K, count(>lo)=count(>=hi)<K).
    const float Tf = __uint_as_float(lo);
    int ge_pack = 0;
#pragma unroll
    for (int b = 0; b < 8; ++b) {
        ge_pack += (__builtin_fabsf(f[b].x) > Tf) ? 1 : 0;
        ge_pack += (__builtin_fabsf(f[b].y) > Tf) ? 1 : 0;
        ge_pack += (__builtin_fabsf(f[b].z) > Tf) ? 1 : 0;
        ge_pack += (__builtin_fabsf(f[b].w) > Tf) ? 1 : 0;
        ge_pack += (__builtin_fabsf(f[b].x) == Tf) ? (1 << 16) : 0;
        ge_pack += (__builtin_fabsf(f[b].y) == Tf) ? (1 << 16) : 0;
        ge_pack += (__builtin_fabsf(f[b].z) == Tf) ? (1 << 16) : 0;
        ge_pack += (__builtin_fabsf(f[b].w) == Tf) ? (1 << 16) : 0;
    }
    const int tot = dpp_reduce_add(ge_pack);
    const int cnt_gt = tot & 0xFFFF;
    const int neq = tot >> 16;
    const int r = K_SEL - cnt_gt;   // equals to keep (1 <= r <= neq)

    if (neq == r) {
#pragma unroll
        for (int b = 0; b < 8; ++b) {
            f32x4 w;
            w.x = (__builtin_fabsf(f[b].x) >= Tf) ? f[b].x * scale : 0.0f;
            w.y = (__builtin_fabsf(f[b].y) >= Tf) ? f[b].y * scale : 0.0f;
            w.z = (__builtin_fabsf(f[b].z) >= Tf) ? f[b].z * scale : 0.0f;
            w.w = (__builtin_fabsf(f[b].w) >= Tf) ? f[b].w * scale : 0.0f;
            __builtin_nontemporal_store(w, op + b * 64 + lane);
        }
        return;
    }

    // Rare: among ==T keep the r with lowest global index
    // (matches lax.top_k stability). Rank via equality ballots.
    // Element (b, lane, e): global index = 256*b + 4*lane + e.
    const unsigned long long lt = (lane == 0) ? 0ull : (~0ull >> (64 - lane));
    int base = 0;  // equals in blocks b' < b
    for (int b = 0; b < 8; ++b) {
        const float fe[4] = { f[b].x, f[b].y, f[b].z, f[b].w };
        unsigned long long m[4];
#pragma unroll
        for (int e = 0; e < 4; ++e) m[e] = __ballot(__builtin_fabsf(fe[e]) == Tf);
        int cm = 0;  // equals in this block from lanes < lane
#pragma unroll
        for (int e = 0; e < 4; ++e) cm += __popcll(m[e] & lt);
        f32x4 w;
        float wv[4];
        int partial = 0;  // equals: same lane, e' < e
#pragma unroll
        for (int e = 0; e < 4; ++e) {
            const int rank = base + cm + partial;
            const bool eq = (__builtin_fabsf(fe[e]) == Tf);
            const bool sel = (__builtin_fabsf(fe[e]) > Tf) || (eq && rank < r);
            wv[e] = sel ? fe[e] * scale : 0.0f;
            partial += (int)((m[e] >> lane) & 1ull);
        }
        w.x = wv[0]; w.y = wv[1]; w.z = wv[2]; w.w = wv[3];
        __builtin_nontemporal_store(w, op + b * 64 + lane);
#pragma unroll
        for (int e = 0; e < 4; ++e) base += __popcll(m[e]);
    }
}

#define LOADBUF(buf, k)                                                   \
    do {                                                                  \
        _Pragma("unroll")                                                 \
        for (int b = 0; b < 8; ++b)                                       \
            buf[b] = gload16(xw + (k) * 512 + b * 64 + lane);             \
    } while (0)

__global__ __launch_bounds__(NT, 2) void sparse_topk_kernel(
        const float* __restrict__ x, float* __restrict__ out) {
    const int wave = threadIdx.x >> 6;
    const int lane = threadIdx.x & 63;
    const long long gw = (long long)blockIdx.x * 4 + wave;   // global wave id
    const long long r0 = gw * RPW;

    const f32x4* xw = reinterpret_cast<const f32x4*>(x + r0 * D_DIM);
    f32x4* ow = reinterpret_cast<f32x4*>(out + r0 * D_DIM);

    f32x4 A[8], B[8], C[8];

    // Prologue: rows 0,1,2 in flight (24 loads outstanding).
    LOADBUF(A, 0);
    LOADBUF(B, 1);
    LOADBUF(C, 2);

    // Loads-only vmcnt budget: W(N), N <= # loads issued after the target.
    VMWAIT(16); process_row(A, ow + 0 * 512, lane); LOADBUF(A, 3);  // r0: Y=L1+L2
    VMWAIT(16); process_row(B, ow + 1 * 512, lane); LOADBUF(B, 4);  // r1: Y=L2+L3
    VMWAIT(16); process_row(C, ow + 2 * 512, lane); LOADBUF(C, 5);  // r2: Y=L3+L4
    VMWAIT(16); process_row(A, ow + 3 * 512, lane); LOADBUF(A, 6);  // r3: Y=L4+L5
    VMWAIT(16); process_row(B, ow + 4 * 512, lane); LOADBUF(B, 7);  // r4: Y=L5+L6
    VMWAIT(16); process_row(C, ow + 5 * 512, lane);                 // r5: Y=L6+L7
    VMWAIT(8);  process_row(A, ow + 6 * 512, lane);                 // r6: Y=L7
    VMWAIT(0);  process_row(B, ow + 7 * 512, lane);                 // r7: Y=0
}

extern "C" void kernel_launch(void* const* d_in, const int* in_sizes, int n_in,
                              void* d_out, int out_size, void* d_ws, size_t ws_size,
                              hipStream_t stream) {
    const float* x = (const float*)d_in[0];
    float* out = (float*)d_out;
    const int rows = in_sizes[0] / D_DIM;            // 16384
    sparse_topk_kernel<<<rows / (4 * RPW), NT, 0, stream>>>(x, out);
}